// Round 11
// baseline (147.361 us; speedup 1.0000x reference)
//
#include <hip/hip_runtime.h>
#include <hip/hip_bf16.h>

#define NPIX 16384   // H*W
#define NC   48      // DIM

typedef __attribute__((ext_vector_type(16))) float f32x16;
typedef __attribute__((ext_vector_type(8))) short short8v;
typedef __attribute__((ext_vector_type(8))) unsigned short ushort8v;
typedef __attribute__((ext_vector_type(2))) unsigned int uint2v;

static __device__ __forceinline__ unsigned short f2bf(float x) {
  union { float f; unsigned u; } v; v.f = x;
  unsigned r = v.u + 0x7fffu + ((v.u >> 16) & 1u);
  return (unsigned short)(r >> 16);
}

// ---------------- kernel 1: pointwise conv  out[o][p] = sum_c w[o][c]*in[c][p]
__global__ __launch_bounds__(256) void k_pointwise(const float* __restrict__ in,
                                                   const float* __restrict__ w,
                                                   float* __restrict__ out) {
  int p = blockIdx.x * 256 + threadIdx.x;
  int og = blockIdx.y * 16;
  __shared__ float wl[16][NC];
  for (int i = threadIdx.x; i < 16 * NC; i += 256)
    wl[i / NC][i % NC] = w[(og + i / NC) * NC + i % NC];
  __syncthreads();
  float acc[16];
#pragma unroll
  for (int j = 0; j < 16; ++j) acc[j] = 0.f;
  for (int c = 0; c < NC; ++c) {
    float xv = in[c * NPIX + p];
#pragma unroll
    for (int j = 0; j < 16; ++j) acc[j] += xv * wl[j][c];
  }
#pragma unroll
  for (int j = 0; j < 16; ++j) out[(og + j) * NPIX + p] = acc[j];
}

// ---------------- kernel 2: depthwise 3x3, SAME zero pad (cross-correlation)
__global__ __launch_bounds__(256) void k_dwconv(const float* __restrict__ in,
                                                const float* __restrict__ w,
                                                float* __restrict__ out) {
  int p = blockIdx.x * 256 + threadIdx.x;
  int o = blockIdx.y;
  int y = p >> 7, xx = p & 127;
  const float* base = in + o * NPIX;
  const float* wt = w + o * 9;
  float acc = 0.f;
#pragma unroll
  for (int dy = -1; dy <= 1; ++dy)
#pragma unroll
    for (int dx = -1; dx <= 1; ++dx) {
      int yy = y + dy, xc = xx + dx;
      if (yy >= 0 && yy < 128 && xc >= 0 && xc < 128)
        acc += wt[(dy + 1) * 3 + (dx + 1)] * base[yy * 128 + xc];
    }
  out[o * NPIX + p] = acc;
}

// ---------------- kernel 3: per-token l2norm of q,k -> bf16.
// q additionally scaled by t*log2(e) so attn softmax uses native exp2.
__global__ __launch_bounds__(64) void k_norm(const float* __restrict__ dwq,
                                             const float* __restrict__ temp,
                                             unsigned short* __restrict__ qn,
                                             unsigned short* __restrict__ kn,
                                             unsigned short* __restrict__ vb) {
  int p = blockIdx.x * 64 + threadIdx.x;
  float t = temp[0] * 1.44269504088896f;  // fold log2(e) into temperature
  float qv[48], kv[48];
  float sq = 0.f, sk = 0.f;
#pragma unroll
  for (int c = 0; c < 48; ++c) {
    qv[c] = dwq[c * NPIX + p];
    kv[c] = dwq[(48 + c) * NPIX + p];
    sq += qv[c] * qv[c];
    sk += kv[c] * kv[c];
  }
  float rq = t / fmaxf(sqrtf(sq), 1e-12f);
  float rk = 1.f / fmaxf(sqrtf(sk), 1e-12f);
  unsigned short qb[48], kb[48];
#pragma unroll
  for (int c = 0; c < 48; ++c) {
    qb[c] = f2bf(qv[c] * rq);
    kb[c] = f2bf(kv[c] * rk);
  }
#pragma unroll
  for (int j = 0; j < 6; ++j) {
    *(ushort8v*)(qn + p * 48 + j * 8) = *(ushort8v*)&qb[j * 8];
    *(ushort8v*)(kn + p * 48 + j * 8) = *(ushort8v*)&kb[j * 8];
  }
#pragma unroll
  for (int c = 0; c < 48; ++c)
    vb[c * NPIX + p] = f2bf(dwq[(96 + c) * NPIX + p]);
}

// ---------------- kernel 4a: MFMA attention NS=8 (round-9 verified structure)
// REGISTER DIET: acc[2][2]->acc[2] (-32 AGPR; 116 VGPR + 64 AGPR = 180 regs
// was capping residency at 2 waves/SIMD) + t-invariant staging offsets hoisted
// (kills per-tile div/mod + swizzle arithmetic). NO min-waves clause — the
// launch_bounds (,N) clause provably corrupts this kernel (r2/r4/r8 vs r9).
// grid 1024: ks=bidx&7 (one split per XCD), qb=bidx>>3.
__global__ __launch_bounds__(256) void k_attn8(const unsigned short* __restrict__ qn,
                                               const unsigned short* __restrict__ kn,
                                               const unsigned short* __restrict__ vb,
                                               float* __restrict__ num) {
  __shared__ __align__(16) char smem[28672];  // K 12288 B + Vt 16384 B (1 buf)
  const int tid = threadIdx.x;
  const int lane = tid & 63, wid = tid >> 6;
  const int l31 = lane & 31, lh = lane >> 5;
  const int bidx = blockIdx.x;
  const int ks = bidx & 7;
  const int qb = bidx >> 3;
  const int qbase = qb * 128 + wid * 32;

  short8v qf[3];
#pragma unroll
  for (int s = 0; s < 3; ++s)
    qf[s] = *(const short8v*)(qn + (qbase + l31) * 48 + s * 16 + lh * 8);

  f32x16 acc[2];  // [c-block] — merged accumulators (reg diet)
#pragma unroll
  for (int b = 0; b < 2; ++b)
#pragma unroll
    for (int r = 0; r < 16; ++r) acc[b][r] = 0.f;

  // t-invariant staging maps: K chunks i=0..2 (chunk=tid+256i in [0,768)),
  // V chunks j=0..2 (cv=tid+256j in [0,768))
  int kgoff[3], kloff[3], vgoff[3], vloff[3];
#pragma unroll
  for (int i = 0; i < 3; ++i) {
    int chunk = tid + 256 * i;
    int key = chunk / 6, part = chunk - key * 6;
    kgoff[i] = key * 48 + part * 8;
    kloff[i] = (key * 96 + part * 16) ^ ((key & 7) << 4);
    int cv = chunk;  // V uses same 0..767 range
    int c2 = cv >> 4, kp = cv & 15;
    vgoff[i] = c2 * NPIX + kp * 8;
    vloff[i] = 12288 + ((c2 * 256 + kp * 16) ^ ((c2 & 7) << 4));
  }

  // Vt pad rows 48..63: row 48 = ones (den), rest zero. Written once.
  {
    int c = 48 + (tid >> 4), kp = tid & 15;
    unsigned short val = (c == 48) ? (unsigned short)0x3F80 : (unsigned short)0;
    ushort8v vv = {val, val, val, val, val, val, val, val};
    *(ushort8v*)(smem + 12288 + ((c * 256 + kp * 16) ^ ((c & 7) << 4))) = vv;
  }
  // prologue: stage tile 0
  {
    const int m0 = ks * 2048;
#pragma unroll
    for (int i = 0; i < 3; ++i) {
      *(short8v*)(smem + kloff[i]) = *(const short8v*)(kn + m0 * 48 + kgoff[i]);
      *(short8v*)(smem + vloff[i]) = *(const short8v*)(vb + m0 + vgoff[i]);
    }
  }
  __syncthreads();

  for (int t = 0; t < 16; ++t) {
    // ---- T14 issue-early: global loads for tile t+1 into registers ----
    short8v pfk[3], pfv[3];
    const bool hasNext = (t + 1 < 16);
    if (hasNext) {
      const int m0n = ks * 2048 + (t + 1) * 128;
#pragma unroll
      for (int i = 0; i < 3; ++i) {
        pfk[i] = *(const short8v*)(kn + m0n * 48 + kgoff[i]);
        pfv[i] = *(const short8v*)(vb + m0n + vgoff[i]);
      }
    }
    // ---- compute tile t ----
#pragma unroll
    for (int kb = 0; kb < 128; kb += 32) {
      f32x16 sacc;
#pragma unroll
      for (int r = 0; r < 16; ++r) sacc[r] = 0.f;
      int key = kb + l31;
#pragma unroll
      for (int s = 0; s < 3; ++s) {
        short8v kf = *(const short8v*)(smem +
            ((key * 96 + s * 32 + lh * 16) ^ ((key & 7) << 4)));
        sacc = __builtin_amdgcn_mfma_f32_32x32x16_bf16(kf, qf[s], sacc, 0, 0, 0);
      }
      float p[16];
#pragma unroll
      for (int r = 0; r < 16; ++r) p[r] = __builtin_amdgcn_exp2f(sacc[r]);
#pragma unroll
      for (int h = 0; h < 2; ++h) {
        unsigned a0, a1, b0, b1;
        asm("v_cvt_pk_bf16_f32 %0, %1, %2" : "=v"(a0) : "v"(p[8 * h + 0]), "v"(p[8 * h + 1]));
        asm("v_cvt_pk_bf16_f32 %0, %1, %2" : "=v"(a1) : "v"(p[8 * h + 2]), "v"(p[8 * h + 3]));
        asm("v_cvt_pk_bf16_f32 %0, %1, %2" : "=v"(b0) : "v"(p[8 * h + 4]), "v"(p[8 * h + 5]));
        asm("v_cvt_pk_bf16_f32 %0, %1, %2" : "=v"(b1) : "v"(p[8 * h + 6]), "v"(p[8 * h + 7]));
        uint2v s0 = __builtin_amdgcn_permlane32_swap(a0, b0, false, false);
        uint2v s1 = __builtin_amdgcn_permlane32_swap(a1, b1, false, false);
        union { unsigned u[4]; short8v v; } pa;
        pa.u[0] = s0[0]; pa.u[1] = s1[0]; pa.u[2] = s0[1]; pa.u[3] = s1[1];
        int kbase = kb + 16 * h + 8 * lh;
        short8v vf0 = *(const short8v*)(smem + 12288 +
            ((l31 * 256 + kbase * 2) ^ ((l31 & 7) << 4)));
        acc[0] = __builtin_amdgcn_mfma_f32_32x32x16_bf16(pa.v, vf0, acc[0], 0, 0, 0);
        int c1 = 32 + l31;
        short8v vf1 = *(const short8v*)(smem + 12288 +
            ((c1 * 256 + kbase * 2) ^ ((c1 & 7) << 4)));
        acc[1] = __builtin_amdgcn_mfma_f32_32x32x16_bf16(pa.v, vf1, acc[1], 0, 0, 0);
      }
    }
    __syncthreads();  // all waves done READING tile t
    // ---- T14 write-late: park prefetched tile t+1 ----
    if (hasNext) {
#pragma unroll
      for (int i = 0; i < 3; ++i) {
        *(short8v*)(smem + kloff[i]) = pfk[i];
        *(short8v*)(smem + vloff[i]) = pfv[i];
      }
    }
    __syncthreads();  // writes visible before next compute
  }

  // ---- epilogue: transpose O through LDS (per-wave [32 q][52 c]), store
  __syncthreads();
  float* ot = (float*)smem + wid * (32 * 52);
#pragma unroll
  for (int r = 0; r < 16; ++r) {
    int q = (r & 3) + 8 * (r >> 2) + 4 * lh;
    ot[q * 52 + l31] = acc[0][r];
    if (l31 < 17) ot[q * 52 + 32 + l31] = acc[1][r];
  }
  __syncthreads();
  for (int idx = lane; idx < 49 * 32; idx += 64) {
    int q = idx & 31, c = idx >> 5;
    num[((ks * 49 + c) << 14) + qbase + q] = ot[q * 52 + c];
  }
}

// ---------------- kernel 4b: EXACT round-7 verified kernel (NS=4 fallback)
__global__ __launch_bounds__(256, 3) void k_attn4(const unsigned short* __restrict__ qn,
                                                  const unsigned short* __restrict__ kn,
                                                  const unsigned short* __restrict__ vb,
                                                  float* __restrict__ num) {
  __shared__ __align__(16) char smem[28672];
  const int tid = threadIdx.x;
  const int lane = tid & 63, wid = tid >> 6;
  const int l31 = lane & 31, lh = lane >> 5;
  const int bidx = blockIdx.x;
  const int xcd = bidx & 7;
  const int ks = xcd & 3;
  const int qb = (xcd >> 2) * 64 + (bidx >> 3);
  const int qbase = qb * 128 + wid * 32;

  short8v qf[3];
#pragma unroll
  for (int s = 0; s < 3; ++s)
    qf[s] = *(const short8v*)(qn + (qbase + l31) * 48 + s * 16 + lh * 8);

  f32x16 acc[2][2];
#pragma unroll
  for (int a = 0; a < 2; ++a)
#pragma unroll
    for (int b = 0; b < 2; ++b)
#pragma unroll
      for (int r = 0; r < 16; ++r) acc[a][b][r] = 0.f;

  {
    int c = 48 + (tid >> 4), kp = tid & 15;
    unsigned short val = (c == 48) ? (unsigned short)0x3F80 : (unsigned short)0;
    ushort8v vv = {val, val, val, val, val, val, val, val};
    *(ushort8v*)(smem + 12288 + ((c * 256 + kp * 16) ^ ((c & 7) << 4))) = vv;
  }
  {
    const int m0 = ks * 4096;
#pragma unroll
    for (int i = 0; i < 6; ++i) {
      int chunk = tid + 256 * i;
      if (chunk < 768) {
        int key = chunk / 6, part = chunk - key * 6;
        short8v kv = *(const short8v*)(kn + (m0 + key) * 48 + part * 8);
        *(short8v*)(smem + ((key * 96 + part * 16) ^ ((key & 7) << 4))) = kv;
      } else {
        int c2 = (chunk - 768) >> 4, kp = (chunk - 768) & 15;
        short8v vv = *(const short8v*)(vb + c2 * NPIX + m0 + kp * 8);
        *(short8v*)(smem + 12288 + ((c2 * 256 + kp * 16) ^ ((c2 & 7) << 4))) = vv;
      }
    }
  }
  __syncthreads();

  for (int t = 0; t < 32; ++t) {
    short8v pf[6];
    const bool hasNext = (t + 1 < 32);
    if (hasNext) {
      const int m0n = ks * 4096 + (t + 1) * 128;
#pragma unroll
      for (int i = 0; i < 6; ++i) {
        int chunk = tid + 256 * i;
        if (chunk < 768) {
          int key = chunk / 6, part = chunk - key * 6;
          pf[i] = *(const short8v*)(kn + (m0n + key) * 48 + part * 8);
        } else {
          int c2 = (chunk - 768) >> 4, kp = (chunk - 768) & 15;
          pf[i] = *(const short8v*)(vb + c2 * NPIX + m0n + kp * 8);
        }
      }
    }
#pragma unroll
    for (int kb = 0; kb < 128; kb += 32) {
      f32x16 sacc;
#pragma unroll
      for (int r = 0; r < 16; ++r) sacc[r] = 0.f;
      int key = kb + l31;
#pragma unroll
      for (int s = 0; s < 3; ++s) {
        short8v kf = *(const short8v*)(smem +
            ((key * 96 + s * 32 + lh * 16) ^ ((key & 7) << 4)));
        sacc = __builtin_amdgcn_mfma_f32_32x32x16_bf16(kf, qf[s], sacc, 0, 0, 0);
      }
      float p[16];
#pragma unroll
      for (int r = 0; r < 16; ++r) p[r] = __builtin_amdgcn_exp2f(sacc[r]);
#pragma unroll
      for (int h = 0; h < 2; ++h) {
        unsigned a0, a1, b0, b1;
        asm("v_cvt_pk_bf16_f32 %0, %1, %2" : "=v"(a0) : "v"(p[8 * h + 0]), "v"(p[8 * h + 1]));
        asm("v_cvt_pk_bf16_f32 %0, %1, %2" : "=v"(a1) : "v"(p[8 * h + 2]), "v"(p[8 * h + 3]));
        asm("v_cvt_pk_bf16_f32 %0, %1, %2" : "=v"(b0) : "v"(p[8 * h + 4]), "v"(p[8 * h + 5]));
        asm("v_cvt_pk_bf16_f32 %0, %1, %2" : "=v"(b1) : "v"(p[8 * h + 6]), "v"(p[8 * h + 7]));
        uint2v s0 = __builtin_amdgcn_permlane32_swap(a0, b0, false, false);
        uint2v s1 = __builtin_amdgcn_permlane32_swap(a1, b1, false, false);
        union { unsigned u[4]; short8v v; } pa;
        pa.u[0] = s0[0]; pa.u[1] = s1[0]; pa.u[2] = s0[1]; pa.u[3] = s1[1];
        int kbase = kb + 16 * h + 8 * lh;
        short8v vf0 = *(const short8v*)(smem + 12288 +
            ((l31 * 256 + kbase * 2) ^ ((l31 & 7) << 4)));
        acc[h][0] = __builtin_amdgcn_mfma_f32_32x32x16_bf16(pa.v, vf0, acc[h][0], 0, 0, 0);
        int c1 = 32 + l31;
        short8v vf1 = *(const short8v*)(smem + 12288 +
            ((c1 * 256 + kbase * 2) ^ ((c1 & 7) << 4)));
        acc[h][1] = __builtin_amdgcn_mfma_f32_32x32x16_bf16(pa.v, vf1, acc[h][1], 0, 0, 0);
      }
    }
    __syncthreads();
    if (hasNext) {
#pragma unroll
      for (int i = 0; i < 6; ++i) {
        int chunk = tid + 256 * i;
        if (chunk < 768) {
          int key = chunk / 6, part = chunk - key * 6;
          *(short8v*)(smem + ((key * 96 + part * 16) ^ ((key & 7) << 4))) = pf[i];
        } else {
          int c2 = (chunk - 768) >> 4, kp = (chunk - 768) & 15;
          *(short8v*)(smem + 12288 + ((c2 * 256 + kp * 16) ^ ((c2 & 7) << 4))) = pf[i];
        }
      }
    }
    __syncthreads();
  }

  f32x16 o0, o1;
#pragma unroll
  for (int r = 0; r < 16; ++r) {
    o0[r] = acc[0][0][r] + acc[1][0][r];
    o1[r] = acc[0][1][r] + acc[1][1][r];
  }
  __syncthreads();
  float* ot = (float*)smem + wid * (32 * 52);
#pragma unroll
  for (int r = 0; r < 16; ++r) {
    int q = (r & 3) + 8 * (r >> 2) + 4 * lh;
    ot[q * 52 + l31] = o0[r];
    if (l31 < 17) ot[q * 52 + 32 + l31] = o1[r];
  }
  __syncthreads();
  for (int idx = lane; idx < 49 * 32; idx += 64) {
    int q = idx & 31, c = idx >> 5;
    num[((ks * 49 + c) << 14) + qbase + q] = ot[q * 52 + c];
  }
}

// ---------------- kernel 5: combine key-splits and divide -> tokT [c][p]
template<int NS>
__global__ __launch_bounds__(256) void k_combine(const float* __restrict__ num,
                                                 float* __restrict__ tokT) {
  int p = blockIdx.x * 256 + threadIdx.x;
  int c = blockIdx.y;
  float d = 0.f, s = 0.f;
#pragma unroll
  for (int ks = 0; ks < NS; ++ks) {
    d += num[(ks * 49 + 48) * NPIX + p];
    s += num[(ks * 49 + c) * NPIX + p];
  }
  tokT[c * NPIX + p] = s / d;
}

extern "C" void kernel_launch(void* const* d_in, const int* in_sizes, int n_in,
                              void* d_out, int out_size, void* d_ws, size_t ws_size,
                              hipStream_t stream) {
  const float* x      = (const float*)d_in[0];
  const float* qkv_w  = (const float*)d_in[1];
  const float* dw_w   = (const float*)d_in[2];
  const float* proj_w = (const float*)d_in[3];
  const float* temp   = (const float*)d_in[4];
  float* ws = (float*)d_ws;

  // workspace (floats):
  //   qkv  [144][16384] @ 0          (dead after dwconv)
  //   dwq  [144][16384] @ 2359296    (dead after norm)
  //   qn/kn bf16 [16384][48] @ 0 / 393216   (overlay dead qkv)
  //   vb   bf16 [48][16384] @ 786432
  //   num  [NS][49][16384] @ 1179648 (overlays dead qkv tail + dwq)
  //   tokT [48][16384] after num
  float* qkv = ws;
  float* dwq = ws + 2359296;
  unsigned short* qn = (unsigned short*)ws;
  unsigned short* kn = (unsigned short*)(ws + 393216);
  unsigned short* vb = (unsigned short*)(ws + 786432);
  float* num = ws + 1179648;

  const bool big = ws_size >= (size_t)8388608 * 4;  // room for NS=8 layout?

  k_pointwise<<<dim3(64, 9), 256, 0, stream>>>(x, qkv_w, qkv);
  k_dwconv<<<dim3(64, 144), 256, 0, stream>>>(qkv, dw_w, dwq);
  k_norm<<<dim3(256), 64, 0, stream>>>(dwq, temp, qn, kn, vb);
  if (big) {
    float* tokT = ws + 7602176;
    k_attn8<<<dim3(1024), 256, 0, stream>>>(qn, kn, vb, num);
    k_combine<8><<<dim3(64, 48), 256, 0, stream>>>(num, tokT);
    k_pointwise<<<dim3(64, 3), 256, 0, stream>>>(tokT, proj_w, (float*)d_out);
  } else {
    float* tokT = ws + 4390912;
    k_attn4<<<dim3(512), 256, 0, stream>>>(qn, kn, vb, num);
    k_combine<4><<<dim3(64, 48), 256, 0, stream>>>(num, tokT);
    k_pointwise<<<dim3(64, 3), 256, 0, stream>>>(tokT, proj_w, (float*)d_out);
  }
}

// Round 12
// 142.401 us; speedup vs baseline: 1.0348x; 1.0348x over previous
//
#include <hip/hip_runtime.h>
#include <hip/hip_bf16.h>

#define NPIX 16384   // H*W
#define NC   48      // DIM

typedef __attribute__((ext_vector_type(16))) float f32x16;
typedef __attribute__((ext_vector_type(8))) short short8v;
typedef __attribute__((ext_vector_type(8))) unsigned short ushort8v;
typedef __attribute__((ext_vector_type(2))) unsigned int uint2v;

static __device__ __forceinline__ unsigned short f2bf(float x) {
  union { float f; unsigned u; } v; v.f = x;
  unsigned r = v.u + 0x7fffu + ((v.u >> 16) & 1u);
  return (unsigned short)(r >> 16);
}
static __device__ __forceinline__ float bf2f(unsigned short b) {
  union { unsigned u; float f; } v; v.u = ((unsigned)b) << 16;
  return v.f;
}

// ---------------- kernel 1: pointwise conv  out[o][p] = sum_c w[o][c]*in[c][p]
__global__ __launch_bounds__(256) void k_pointwise(const float* __restrict__ in,
                                                   const float* __restrict__ w,
                                                   float* __restrict__ out) {
  int p = blockIdx.x * 256 + threadIdx.x;
  int og = blockIdx.y * 16;
  __shared__ float wl[16][NC];
  for (int i = threadIdx.x; i < 16 * NC; i += 256)
    wl[i / NC][i % NC] = w[(og + i / NC) * NC + i % NC];
  __syncthreads();
  float acc[16];
#pragma unroll
  for (int j = 0; j < 16; ++j) acc[j] = 0.f;
  for (int c = 0; c < NC; ++c) {
    float xv = in[c * NPIX + p];
#pragma unroll
    for (int j = 0; j < 16; ++j) acc[j] += xv * wl[j][c];
  }
#pragma unroll
  for (int j = 0; j < 16; ++j) out[(og + j) * NPIX + p] = acc[j];
}

// ---------------- kernel 2: depthwise 3x3, SAME pad; writes bf16 channel-major
__global__ __launch_bounds__(256) void k_dwconv(const float* __restrict__ in,
                                                const float* __restrict__ w,
                                                unsigned short* __restrict__ out) {
  int p = blockIdx.x * 256 + threadIdx.x;
  int o = blockIdx.y;
  int y = p >> 7, xx = p & 127;
  const float* base = in + o * NPIX;
  const float* wt = w + o * 9;
  float acc = 0.f;
#pragma unroll
  for (int dy = -1; dy <= 1; ++dy)
#pragma unroll
    for (int dx = -1; dx <= 1; ++dx) {
      int yy = y + dy, xc = xx + dx;
      if (yy >= 0 && yy < 128 && xc >= 0 && xc < 128)
        acc += wt[(dy + 1) * 3 + (dx + 1)] * base[yy * 128 + xc];
    }
  out[o * NPIX + p] = f2bf(acc);
}

// ---------------- kernel 3: per-token l2norm of q,k (bf16 in) -> bf16 out.
// q additionally scaled by t*log2(e) so attn softmax uses native exp2.
// v channels (96..143) need no copy: dwconv already wrote them in vb layout.
__global__ __launch_bounds__(64) void k_norm(const unsigned short* __restrict__ dwqb,
                                             const float* __restrict__ temp,
                                             unsigned short* __restrict__ qn,
                                             unsigned short* __restrict__ kn) {
  int p = blockIdx.x * 64 + threadIdx.x;
  float t = temp[0] * 1.44269504088896f;  // fold log2(e) into temperature
  float qv[48], kv[48];
  float sq = 0.f, sk = 0.f;
#pragma unroll
  for (int c = 0; c < 48; ++c) {
    qv[c] = bf2f(dwqb[c * NPIX + p]);
    kv[c] = bf2f(dwqb[(48 + c) * NPIX + p]);
    sq += qv[c] * qv[c];
    sk += kv[c] * kv[c];
  }
  float rq = t / fmaxf(sqrtf(sq), 1e-12f);
  float rk = 1.f / fmaxf(sqrtf(sk), 1e-12f);
  unsigned short qb[48], kb[48];
#pragma unroll
  for (int c = 0; c < 48; ++c) {
    qb[c] = f2bf(qv[c] * rq);
    kb[c] = f2bf(kv[c] * rk);
  }
#pragma unroll
  for (int j = 0; j < 6; ++j) {
    *(ushort8v*)(qn + p * 48 + j * 8) = *(ushort8v*)&qb[j * 8];
    *(ushort8v*)(kn + p * 48 + j * 8) = *(ushort8v*)&kb[j * 8];
  }
}

// ---------------- kernel 4: MFMA attention NS=8 (round-10 verified structure)
// SWIZZLE FIX: Vt rows are 256 B; old ((c&7)<<4) left PV V-reads 4-way bank
// conflicted (32 lanes -> 8 slots). ((c&15)<<4) is bijective over the 16
// 16B-slots per row -> 2-way (free, m136). Applied at ALL Vt sites.
// NO min-waves clause — (,4) provably corrupts this kernel (r8 vs r9).
// grid 1024: ks=bidx&7 (one split per XCD), qb=bidx>>3.
__global__ __launch_bounds__(256) void k_attn8(const unsigned short* __restrict__ qn,
                                               const unsigned short* __restrict__ kn,
                                               const unsigned short* __restrict__ vb,
                                               float* __restrict__ num) {
  __shared__ __align__(16) char smem[28672];  // K 12288 B + Vt 16384 B (1 buf)
  const int tid = threadIdx.x;
  const int lane = tid & 63, wid = tid >> 6;
  const int l31 = lane & 31, lh = lane >> 5;
  const int bidx = blockIdx.x;
  const int ks = bidx & 7;
  const int qb = bidx >> 3;
  const int qbase = qb * 128 + wid * 32;

  short8v qf[3];
#pragma unroll
  for (int s = 0; s < 3; ++s)
    qf[s] = *(const short8v*)(qn + (qbase + l31) * 48 + s * 16 + lh * 8);

  f32x16 acc[2];  // [c-block]
#pragma unroll
  for (int b = 0; b < 2; ++b)
#pragma unroll
    for (int r = 0; r < 16; ++r) acc[b][r] = 0.f;

  // t-invariant staging maps
  int kgoff[3], kloff[3], vgoff[3], vloff[3];
#pragma unroll
  for (int i = 0; i < 3; ++i) {
    int chunk = tid + 256 * i;
    int key = chunk / 6, part = chunk - key * 6;
    kgoff[i] = key * 48 + part * 8;
    kloff[i] = (key * 96 + part * 16) ^ ((key & 7) << 4);
    int c2 = chunk >> 4, kp = chunk & 15;
    vgoff[i] = c2 * NPIX + kp * 8;
    vloff[i] = 12288 + ((c2 * 256 + kp * 16) ^ ((c2 & 15) << 4));
  }

  // Vt pad rows 48..63: row 48 = ones (den), rest zero. Written once.
  {
    int c = 48 + (tid >> 4), kp = tid & 15;
    unsigned short val = (c == 48) ? (unsigned short)0x3F80 : (unsigned short)0;
    ushort8v vv = {val, val, val, val, val, val, val, val};
    *(ushort8v*)(smem + 12288 + ((c * 256 + kp * 16) ^ ((c & 15) << 4))) = vv;
  }
  // prologue: stage tile 0
  {
    const int m0 = ks * 2048;
#pragma unroll
    for (int i = 0; i < 3; ++i) {
      *(short8v*)(smem + kloff[i]) = *(const short8v*)(kn + m0 * 48 + kgoff[i]);
      *(short8v*)(smem + vloff[i]) = *(const short8v*)(vb + m0 + vgoff[i]);
    }
  }
  __syncthreads();

  for (int t = 0; t < 16; ++t) {
    // ---- T14 issue-early: global loads for tile t+1 into registers ----
    short8v pfk[3], pfv[3];
    const bool hasNext = (t + 1 < 16);
    if (hasNext) {
      const int m0n = ks * 2048 + (t + 1) * 128;
#pragma unroll
      for (int i = 0; i < 3; ++i) {
        pfk[i] = *(const short8v*)(kn + m0n * 48 + kgoff[i]);
        pfv[i] = *(const short8v*)(vb + m0n + vgoff[i]);
      }
    }
    // ---- compute tile t ----
#pragma unroll
    for (int kb = 0; kb < 128; kb += 32) {
      f32x16 sacc;
#pragma unroll
      for (int r = 0; r < 16; ++r) sacc[r] = 0.f;
      int key = kb + l31;
#pragma unroll
      for (int s = 0; s < 3; ++s) {
        short8v kf = *(const short8v*)(smem +
            ((key * 96 + s * 32 + lh * 16) ^ ((key & 7) << 4)));
        sacc = __builtin_amdgcn_mfma_f32_32x32x16_bf16(kf, qf[s], sacc, 0, 0, 0);
      }
      float p[16];
#pragma unroll
      for (int r = 0; r < 16; ++r) p[r] = __builtin_amdgcn_exp2f(sacc[r]);
#pragma unroll
      for (int h = 0; h < 2; ++h) {
        unsigned a0, a1, b0, b1;
        asm("v_cvt_pk_bf16_f32 %0, %1, %2" : "=v"(a0) : "v"(p[8 * h + 0]), "v"(p[8 * h + 1]));
        asm("v_cvt_pk_bf16_f32 %0, %1, %2" : "=v"(a1) : "v"(p[8 * h + 2]), "v"(p[8 * h + 3]));
        asm("v_cvt_pk_bf16_f32 %0, %1, %2" : "=v"(b0) : "v"(p[8 * h + 4]), "v"(p[8 * h + 5]));
        asm("v_cvt_pk_bf16_f32 %0, %1, %2" : "=v"(b1) : "v"(p[8 * h + 6]), "v"(p[8 * h + 7]));
        uint2v s0 = __builtin_amdgcn_permlane32_swap(a0, b0, false, false);
        uint2v s1 = __builtin_amdgcn_permlane32_swap(a1, b1, false, false);
        union { unsigned u[4]; short8v v; } pa;
        pa.u[0] = s0[0]; pa.u[1] = s1[0]; pa.u[2] = s0[1]; pa.u[3] = s1[1];
        int kbase = kb + 16 * h + 8 * lh;
        short8v vf0 = *(const short8v*)(smem + 12288 +
            ((l31 * 256 + kbase * 2) ^ ((l31 & 15) << 4)));
        acc[0] = __builtin_amdgcn_mfma_f32_32x32x16_bf16(pa.v, vf0, acc[0], 0, 0, 0);
        int c1 = 32 + l31;
        short8v vf1 = *(const short8v*)(smem + 12288 +
            ((c1 * 256 + kbase * 2) ^ ((c1 & 15) << 4)));
        acc[1] = __builtin_amdgcn_mfma_f32_32x32x16_bf16(pa.v, vf1, acc[1], 0, 0, 0);
      }
    }
    __syncthreads();  // all waves done READING tile t
    // ---- T14 write-late: park prefetched tile t+1 ----
    if (hasNext) {
#pragma unroll
      for (int i = 0; i < 3; ++i) {
        *(short8v*)(smem + kloff[i]) = pfk[i];
        *(short8v*)(smem + vloff[i]) = pfv[i];
      }
    }
    __syncthreads();  // writes visible before next compute
  }

  // ---- epilogue: transpose O through LDS (per-wave [32 q][52 c]), store
  __syncthreads();
  float* ot = (float*)smem + wid * (32 * 52);
#pragma unroll
  for (int r = 0; r < 16; ++r) {
    int q = (r & 3) + 8 * (r >> 2) + 4 * lh;
    ot[q * 52 + l31] = acc[0][r];
    if (l31 < 17) ot[q * 52 + 32 + l31] = acc[1][r];
  }
  __syncthreads();
  for (int idx = lane; idx < 49 * 32; idx += 64) {
    int q = idx & 31, c = idx >> 5;
    num[((ks * 49 + c) << 14) + qbase + q] = ot[q * 52 + c];
  }
}

// ---------------- kernel 5: combine key-splits and divide -> tokT [c][p]
__global__ __launch_bounds__(256) void k_combine(const float* __restrict__ num,
                                                 float* __restrict__ tokT) {
  int p = blockIdx.x * 256 + threadIdx.x;
  int c = blockIdx.y;
  float d = 0.f, s = 0.f;
#pragma unroll
  for (int ks = 0; ks < 8; ++ks) {
    d += num[(ks * 49 + 48) * NPIX + p];
    s += num[(ks * 49 + c) * NPIX + p];
  }
  tokT[c * NPIX + p] = s / d;
}

extern "C" void kernel_launch(void* const* d_in, const int* in_sizes, int n_in,
                              void* d_out, int out_size, void* d_ws, size_t ws_size,
                              hipStream_t stream) {
  const float* x      = (const float*)d_in[0];
  const float* qkv_w  = (const float*)d_in[1];
  const float* dw_w   = (const float*)d_in[2];
  const float* proj_w = (const float*)d_in[3];
  const float* temp   = (const float*)d_in[4];

  // workspace layout (bytes), peak 33.55 MB (== proven-available r9/r10):
  //   qn   bf16 [16384][48] @ 0         (1.5 MB; dead after attn)
  //   kn   bf16 [16384][48] @ 1572864   (1.5 MB; dead after attn)
  //   dwqb bf16 [144][16384] @ 3145728  (4.7 MB; ch 96..143 = vb, live in attn)
  //   qkv  f32  [144][16384] @ 7864320  (9.4 MB; dead after dwconv)
  //   num  f32  [8][49][16384] @ 7864320 (25.7 MB; overlays dead qkv)
  //   tokT f32  [48][16384] @ 0         (3.1 MB; overlays dead qn/kn/dwqb-head)
  char* wsb = (char*)d_ws;
  unsigned short* qn   = (unsigned short*)wsb;
  unsigned short* kn   = (unsigned short*)(wsb + 1572864);
  unsigned short* dwqb = (unsigned short*)(wsb + 3145728);
  unsigned short* vb   = dwqb + 96 * NPIX;
  float* qkv  = (float*)(wsb + 7864320);
  float* num  = (float*)(wsb + 7864320);
  float* tokT = (float*)wsb;

  k_pointwise<<<dim3(64, 9), 256, 0, stream>>>(x, qkv_w, qkv);
  k_dwconv<<<dim3(64, 144), 256, 0, stream>>>(qkv, dw_w, dwqb);
  k_norm<<<dim3(256), 64, 0, stream>>>(dwqb, temp, qn, kn);
  k_attn8<<<dim3(1024), 256, 0, stream>>>(qn, kn, vb, num);
  k_combine<<<dim3(64, 48), 256, 0, stream>>>(num, tokT);
  k_pointwise<<<dim3(64, 3), 256, 0, stream>>>(tokT, proj_w, (float*)d_out);
}